// Round 1
// baseline (4849.634 us; speedup 1.0000x reference)
//
#include <hip/hip_runtime.h>

#define N_ENT 14951
#define N_REL 1345
#define NNODE 120000
#define NEDGE 480000

static inline int ceil_div(int a, int b){ return (a + b - 1) / b; }

__device__ inline unsigned fenc(float f){
  unsigned u = __float_as_uint(f);
  return (u & 0x80000000u) ? ~u : (u | 0x80000000u);
}
__device__ inline float fdec(unsigned u){
  return (u & 0x80000000u) ? __uint_as_float(u & 0x7fffffffu) : __uint_as_float(~u);
}

// ---------------- generic f32 GEMM: C[M,N] = concat(A1,A2)[M,K] @ B[K,N] (+bias)(+relu)
// A element (r,k) = k<K1 ? A1[r*K1+k] : A2[r*(K-K1)+(k-K1)]. All K multiples of 4.
template<bool RELU, bool HASBIAS>
__global__ __launch_bounds__(256) void gemm_f32(
    const float* __restrict__ A1, int K1, const float* __restrict__ A2,
    const float* __restrict__ B, const float* __restrict__ bias,
    float* __restrict__ C, int M, int K, int N)
{
  constexpr int BM = 64, BN = 128, BK = 16;
  __shared__ float As[BK][BM + 4];
  __shared__ float Bs[BK][BN];
  const int t = threadIdx.x;
  const int m0 = blockIdx.y * BM, n0 = blockIdx.x * BN;
  const int tr = t >> 4, tc = t & 15;
  const int tm0 = tr * 4, tn0 = tc * 8;
  const int K2 = K - K1;
  const int arow = t >> 2, aq = (t & 3) * 4;
  const int brow = t >> 4, bc0 = (t & 15) * 4;
  float acc[4][8];
  #pragma unroll
  for (int i = 0; i < 4; i++)
    #pragma unroll
    for (int j = 0; j < 8; j++) acc[i][j] = 0.f;

  for (int k0 = 0; k0 < K; k0 += BK) {
    { // A tile -> As[k][m]
      const int r = m0 + arow;
      const int k = k0 + aq;
      float4 v = make_float4(0.f, 0.f, 0.f, 0.f);
      if (r < M) {
        if (k + 3 < K1) {
          v = *(const float4*)(A1 + (size_t)r * K1 + k);
        } else if (k >= K1 && (k - K1) + 3 < K2) {
          v = *(const float4*)(A2 + (size_t)r * K2 + (k - K1));
        } else {
          float tmp[4] = {0.f, 0.f, 0.f, 0.f};
          #pragma unroll
          for (int j = 0; j < 4; j++) {
            int kj = k + j;
            if (kj < K) tmp[j] = (kj < K1) ? A1[(size_t)r * K1 + kj]
                                           : A2[(size_t)r * K2 + (kj - K1)];
          }
          v = make_float4(tmp[0], tmp[1], tmp[2], tmp[3]);
        }
      }
      As[aq + 0][arow] = v.x; As[aq + 1][arow] = v.y;
      As[aq + 2][arow] = v.z; As[aq + 3][arow] = v.w;
    }
    { // B tile
      const int k = k0 + brow;
      #pragma unroll
      for (int h = 0; h < 2; h++) {
        const int n = n0 + bc0 + h * 64;
        float4 v = make_float4(0.f, 0.f, 0.f, 0.f);
        if (k < K) {
          if (n + 3 < N) {
            v = *(const float4*)(B + (size_t)k * N + n);
          } else {
            float tmp[4] = {0.f, 0.f, 0.f, 0.f};
            for (int j = 0; j < 4; j++) if (n + j < N) tmp[j] = B[(size_t)k * N + n + j];
            v = make_float4(tmp[0], tmp[1], tmp[2], tmp[3]);
          }
        }
        *(float4*)&Bs[brow][bc0 + h * 64] = v;
      }
    }
    __syncthreads();
    #pragma unroll
    for (int k = 0; k < BK; k++) {
      float a[4], b[8];
      *(float4*)&a[0] = *(const float4*)&As[k][tm0];
      *(float4*)&b[0] = *(const float4*)&Bs[k][tn0];
      *(float4*)&b[4] = *(const float4*)&Bs[k][tn0 + 4];
      #pragma unroll
      for (int i = 0; i < 4; i++)
        #pragma unroll
        for (int j = 0; j < 8; j++) acc[i][j] = fmaf(a[i], b[j], acc[i][j]);
    }
    __syncthreads();
  }
  #pragma unroll
  for (int i = 0; i < 4; i++) {
    const int r = m0 + tm0 + i;
    if (r >= M) continue;
    #pragma unroll
    for (int j = 0; j < 8; j++) {
      const int c = n0 + tn0 + j;
      if (c >= N) continue;
      float v = acc[i][j];
      if (HASBIAS) v += bias[c];
      if (RELU) v = fmaxf(v, 0.f);
      C[(size_t)r * N + c] = v;
    }
  }
}

// ---------------- spmm1 fused with double gather: out[dst] += w*(eg1[bx[src]] + rg1[bg[src]]), 256 cols
__global__ __launch_bounds__(256) void spmm1_k(
    const int* __restrict__ esrc, const int* __restrict__ edst, const float* __restrict__ ew,
    const int* __restrict__ bx, const int* __restrict__ bg,
    const float* __restrict__ eg1, const float* __restrict__ rg1,
    float* __restrict__ out)
{
  const int gid = blockIdx.x * blockDim.x + threadIdx.x;
  const int e = gid >> 6;
  const int lane = gid & 63;
  if (e >= NEDGE) return;
  const int s = esrc[e], d = edst[e];
  const float w = ew[e];
  const int en = bx[s], gn = bg[s];
  const float4 v = ((const float4*)(eg1 + (size_t)en * 256))[lane];
  const float4 u = ((const float4*)(rg1 + (size_t)gn * 256))[lane];
  float* po = out + (size_t)d * 256 + lane * 4;
  atomicAdd(po + 0, w * (v.x + u.x));
  atomicAdd(po + 1, w * (v.y + u.y));
  atomicAdd(po + 2, w * (v.z + u.z));
  atomicAdd(po + 3, w * (v.w + u.w));
}

// ---------------- spmm2: out[dst] += w*src[srcnode], 200 cols
__global__ __launch_bounds__(256) void spmm2_k(
    const int* __restrict__ esrc, const int* __restrict__ edst, const float* __restrict__ ew,
    const float* __restrict__ src, float* __restrict__ out)
{
  const int gid = blockIdx.x * blockDim.x + threadIdx.x;
  const int e = gid >> 6;
  const int lane = gid & 63;
  if (e >= NEDGE) return;
  if (lane >= 50) return;
  const int s = esrc[e], d = edst[e];
  const float w = ew[e];
  const float4 v = ((const float4*)(src + (size_t)s * 200))[lane];
  float* po = out + (size_t)d * 200 + lane * 4;
  atomicAdd(po + 0, w * v.x);
  atomicAdd(po + 1, w * v.y);
  atomicAdd(po + 2, w * v.z);
  atomicAdd(po + 3, w * v.w);
}

// ---------------- elementwise bias (+relu), float4 granularity
template<bool RELU>
__global__ __launch_bounds__(256) void bias_k(float* __restrict__ h, const float* __restrict__ bias,
                                              int ncol4, size_t total4)
{
  size_t i = (size_t)blockIdx.x * blockDim.x + threadIdx.x;
  if (i >= total4) return;
  int c4 = (int)(i % (size_t)ncol4);
  float4 v = ((float4*)h)[i];
  const float4 b = ((const float4*)bias)[c4];
  v.x += b.x; v.y += b.y; v.z += b.z; v.w += b.w;
  if (RELU) { v.x = fmaxf(v.x, 0.f); v.y = fmaxf(v.y, 0.f); v.z = fmaxf(v.z, 0.f); v.w = fmaxf(v.w, 0.f); }
  ((float4*)h)[i] = v;
}

// ---------------- per-node segment sum into embE[:,200:400] + counts
__global__ __launch_bounds__(256) void seg_sum_k(
    const float* __restrict__ h2, const int* __restrict__ bx,
    float* __restrict__ embE, float* __restrict__ cnt)
{
  const int gid = blockIdx.x * blockDim.x + threadIdx.x;
  const int i = gid >> 6, lane = gid & 63;
  if (i >= NNODE) return;
  const int ent = bx[i];
  if (lane == 0) atomicAdd(&cnt[ent], 1.0f);
  if (lane < 50) {
    const float4 v = ((const float4*)(h2 + (size_t)i * 200))[lane];
    float* p = embE + (size_t)ent * 400 + 200 + lane * 4;
    atomicAdd(p + 0, v.x); atomicAdd(p + 1, v.y);
    atomicAdd(p + 2, v.z); atomicAdd(p + 3, v.w);
  }
}

__global__ __launch_bounds__(256) void mean_div_k(float* __restrict__ embE, const float* __restrict__ cnt)
{
  int i = blockIdx.x * blockDim.x + threadIdx.x;
  if (i >= N_ENT * 50) return;
  int ent = i / 50, c4 = i % 50;
  float inv = 1.0f / fmaxf(cnt[ent], 1.0f);
  float4* p = (float4*)(embE + (size_t)ent * 400 + 200) + c4;
  float4 v = *p;
  v.x *= inv; v.y *= inv; v.z *= inv; v.w *= inv;
  *p = v;
}

__device__ inline float wave_dot200(const float* __restrict__ a, const float* __restrict__ b, int lane)
{
  float s = 0.f;
  if (lane < 50) {
    const float4 x = ((const float4*)a)[lane];
    const float4 y = ((const float4*)b)[lane];
    s = x.x * y.x + x.y * y.y + x.z * y.z + x.w * y.w;
  }
  for (int off = 32; off; off >>= 1) s += __shfl_down(s, off);
  return s;
}

__global__ __launch_bounds__(256) void meanw_k(const float* __restrict__ embE,
                                               const float* __restrict__ W_e,
                                               float* __restrict__ mw)
{
  const int gid = blockIdx.x * blockDim.x + threadIdx.x;
  const int i = gid >> 6, lane = gid & 63;
  if (i >= N_ENT) return;
  float s = wave_dot200(embE + (size_t)i * 400 + 200, W_e + 200, lane);
  if (lane == 0) mw[i] = s;
}

__global__ __launch_bounds__(256) void score_k(const float* __restrict__ h2, const int* __restrict__ bx,
                                               const float* __restrict__ mw, const float* __restrict__ W_e,
                                               const float* __restrict__ b_e, float* __restrict__ score)
{
  const int gid = blockIdx.x * blockDim.x + threadIdx.x;
  const int i = gid >> 6, lane = gid & 63;
  if (i >= NNODE) return;
  float s = wave_dot200(h2 + (size_t)i * 200, W_e, lane);
  if (lane == 0) score[i] = s + mw[bx[i]] + b_e[0];
}

__global__ __launch_bounds__(256) void smax_k(const float* __restrict__ score, const int* __restrict__ bx,
                                              unsigned* __restrict__ smax)
{
  int i = blockIdx.x * blockDim.x + threadIdx.x;
  if (i >= NNODE) return;
  atomicMax(&smax[bx[i]], fenc(score[i]));
}

__global__ __launch_bounds__(256) void expsum_k(float* __restrict__ score, const int* __restrict__ bx,
                                                const unsigned* __restrict__ smax, float* __restrict__ esum)
{
  int i = blockIdx.x * blockDim.x + threadIdx.x;
  if (i >= NNODE) return;
  float m = fdec(smax[bx[i]]);
  float e = __expf(score[i] - m);
  score[i] = e;
  atomicAdd(&esum[bx[i]], e);
}

__global__ __launch_bounds__(256) void wsum_k(const float* __restrict__ h2, const float* __restrict__ score,
                                              const int* __restrict__ bx, const float* __restrict__ esum,
                                              float* __restrict__ embE)
{
  const int gid = blockIdx.x * blockDim.x + threadIdx.x;
  const int i = gid >> 6, lane = gid & 63;
  if (i >= NNODE) return;
  const int ent = bx[i];
  const float z = score[i] / esum[ent];
  if (lane < 50) {
    const float4 v = ((const float4*)(h2 + (size_t)i * 200))[lane];
    float* p = embE + (size_t)ent * 400 + lane * 4;
    atomicAdd(p + 0, z * v.x); atomicAdd(p + 1, z * v.y);
    atomicAdd(p + 2, z * v.z); atomicAdd(p + 3, z * v.w);
  }
}

extern "C" void kernel_launch(void* const* d_in, const int* in_sizes, int n_in,
                              void* d_out, int out_size, void* d_ws, size_t ws_size,
                              hipStream_t stream)
{
  const float* img  = (const float*)d_in[0];
  const float* txt  = (const float*)d_in[1];
  const float* rel  = (const float*)d_in[2];
  const float* W_it = (const float*)d_in[3];
  const float* b_it = (const float*)d_in[4];
  const float* W_ri = (const float*)d_in[5];
  const float* b_ri = (const float*)d_in[6];
  const float* W_g1 = (const float*)d_in[7];
  const float* b_g1 = (const float*)d_in[8];
  const float* W_g2 = (const float*)d_in[9];
  const float* b_g2 = (const float*)d_in[10];
  const float* W_e  = (const float*)d_in[11];
  const float* b_e  = (const float*)d_in[12];
  const float* W_eo = (const float*)d_in[13];
  const float* b_eo = (const float*)d_in[14];
  const float* W_r  = (const float*)d_in[15];
  const float* b_r  = (const float*)d_in[16];
  const float* ew   = (const float*)d_in[17];
  const int*   bx   = (const int*)d_in[18];
  const int*   bg   = (const int*)d_in[19];
  const int*   esrc = (const int*)d_in[20];
  const int*   edst = (const int*)d_in[21];

  float* ws = (float*)d_ws;
  size_t off = 0;
  auto alloc = [&](size_t n){ size_t r = off; off += (n + 255) & ~(size_t)255; return r; };
  float* emf  = ws + alloc((size_t)N_ENT * 100);
  float* rin  = ws + alloc((size_t)N_REL * 100);
  float* eg1  = ws + alloc((size_t)N_ENT * 256);
  float* rg1  = ws + alloc((size_t)N_REL * 256);
  float* big1 = ws + alloc((size_t)NNODE * 256);   // s1/h1, then h2 reuses first NNODE*200
  float* hg2  = ws + alloc((size_t)NNODE * 200);
  float* embE = ws + alloc((size_t)N_ENT * 400);   // [:,0:200]=wsum, [:,200:400]=mean
  float* cnt  = ws + alloc(N_ENT);
  float* mw   = ws + alloc(N_ENT);
  float* esum = ws + alloc(N_ENT);
  unsigned* smax = (unsigned*)(ws + alloc(N_ENT));
  float* score = ws + alloc(NNODE);
  float* h2 = big1;

  hipMemsetAsync(big1, 0, (size_t)NNODE * 256 * 4, stream);
  hipMemsetAsync(embE, 0, (size_t)N_ENT * 400 * 4, stream);
  hipMemsetAsync(cnt,  0, (size_t)N_ENT * 4, stream);
  hipMemsetAsync(esum, 0, (size_t)N_ENT * 4, stream);
  hipMemsetAsync(smax, 0, (size_t)N_ENT * 4, stream);

  dim3 blk(256);

  // encoder GEMMs
  gemm_f32<false, true><<<dim3(1, ceil_div(N_ENT, 64)), blk, 0, stream>>>(
      img, 4096, txt, W_it, b_it, emf, N_ENT, 4396, 100);
  gemm_f32<true, true><<<dim3(1, ceil_div(N_REL, 64)), blk, 0, stream>>>(
      rel, 300, rel, W_ri, b_ri, rin, N_REL, 300, 100);
  gemm_f32<false, false><<<dim3(2, ceil_div(N_ENT, 64)), blk, 0, stream>>>(
      emf, 100, emf, W_g1, nullptr, eg1, N_ENT, 100, 256);
  gemm_f32<false, false><<<dim3(2, ceil_div(N_REL, 64)), blk, 0, stream>>>(
      rin, 100, rin, W_g1 + 100 * 256, nullptr, rg1, N_REL, 100, 256);

  // GCN layer 1: s1 = spmm(eg1[bx]+rg1[bg]); h1 = relu(s1 + b_gc1)
  spmm1_k<<<ceil_div(NEDGE, 4), blk, 0, stream>>>(esrc, edst, ew, bx, bg, eg1, rg1, big1);
  bias_k<true><<<ceil_div(NNODE * 64, 256), blk, 0, stream>>>(big1, b_g1, 64, (size_t)NNODE * 64);

  // GCN layer 2: hg2 = h1 @ W_gc2; h2 = spmm(hg2) + b_gc2
  gemm_f32<false, false><<<dim3(2, ceil_div(NNODE, 64)), blk, 0, stream>>>(
      big1, 256, big1, W_g2, nullptr, hg2, NNODE, 256, 200);
  hipMemsetAsync(h2, 0, (size_t)NNODE * 200 * 4, stream);
  spmm2_k<<<ceil_div(NEDGE, 4), blk, 0, stream>>>(esrc, edst, ew, hg2, h2);
  bias_k<false><<<ceil_div(NNODE * 50, 256), blk, 0, stream>>>(h2, b_g2, 50, (size_t)NNODE * 50);

  // scatter-mean
  seg_sum_k<<<ceil_div(NNODE * 64, 256), blk, 0, stream>>>(h2, bx, embE, cnt);
  mean_div_k<<<ceil_div(N_ENT * 50, 256), blk, 0, stream>>>(embE, cnt);

  // scores + segment softmax + weighted segment sum
  meanw_k<<<ceil_div(N_ENT * 64, 256), blk, 0, stream>>>(embE, W_e, mw);
  score_k<<<ceil_div(NNODE * 64, 256), blk, 0, stream>>>(h2, bx, mw, W_e, b_e, score);
  smax_k<<<ceil_div(NNODE, 256), blk, 0, stream>>>(score, bx, smax);
  expsum_k<<<ceil_div(NNODE, 256), blk, 0, stream>>>(score, bx, smax, esum);
  wsum_k<<<ceil_div(NNODE * 64, 256), blk, 0, stream>>>(h2, score, bx, esum, embE);

  // final projections
  float* out_new = (float*)d_out;
  float* out_rel = out_new + (size_t)N_ENT * 200;
  gemm_f32<false, true><<<dim3(2, ceil_div(N_ENT, 64)), blk, 0, stream>>>(
      embE, 400, embE, W_eo, b_eo, out_new, N_ENT, 400, 200);
  gemm_f32<true, true><<<dim3(2, ceil_div(N_REL, 64)), blk, 0, stream>>>(
      rel, 300, rel, W_r, b_r, out_rel, N_REL, 300, 200);
}

// Round 2
// 1589.650 us; speedup vs baseline: 3.0508x; 3.0508x over previous
//
#include <hip/hip_runtime.h>

#define N_ENT 14951
#define N_REL 1345
#define NNODE 120000
#define NEDGE 480000

static inline int ceil_div(int a, int b){ return (a + b - 1) / b; }

// ---------------- generic f32 GEMM: C[M,N] = concat(A1,A2)[M,K] @ B[K,N] (+bias)(+relu)
template<bool RELU, bool HASBIAS>
__global__ __launch_bounds__(256) void gemm_f32(
    const float* __restrict__ A1, int K1, const float* __restrict__ A2,
    const float* __restrict__ B, const float* __restrict__ bias,
    float* __restrict__ C, int M, int K, int N)
{
  constexpr int BM = 64, BN = 128, BK = 16;
  __shared__ float As[BK][BM + 4];
  __shared__ float Bs[BK][BN];
  const int t = threadIdx.x;
  const int m0 = blockIdx.y * BM, n0 = blockIdx.x * BN;
  const int tr = t >> 4, tc = t & 15;
  const int tm0 = tr * 4, tn0 = tc * 8;
  const int K2 = K - K1;
  const int arow = t >> 2, aq = (t & 3) * 4;
  const int brow = t >> 4, bc0 = (t & 15) * 4;
  float acc[4][8];
  #pragma unroll
  for (int i = 0; i < 4; i++)
    #pragma unroll
    for (int j = 0; j < 8; j++) acc[i][j] = 0.f;

  for (int k0 = 0; k0 < K; k0 += BK) {
    { // A tile -> As[k][m]
      const int r = m0 + arow;
      const int k = k0 + aq;
      float4 v = make_float4(0.f, 0.f, 0.f, 0.f);
      if (r < M) {
        if (k + 3 < K1) {
          v = *(const float4*)(A1 + (size_t)r * K1 + k);
        } else if (k >= K1 && (k - K1) + 3 < K2) {
          v = *(const float4*)(A2 + (size_t)r * K2 + (k - K1));
        } else {
          float tmp[4] = {0.f, 0.f, 0.f, 0.f};
          #pragma unroll
          for (int j = 0; j < 4; j++) {
            int kj = k + j;
            if (kj < K) tmp[j] = (kj < K1) ? A1[(size_t)r * K1 + kj]
                                           : A2[(size_t)r * K2 + (kj - K1)];
          }
          v = make_float4(tmp[0], tmp[1], tmp[2], tmp[3]);
        }
      }
      As[aq + 0][arow] = v.x; As[aq + 1][arow] = v.y;
      As[aq + 2][arow] = v.z; As[aq + 3][arow] = v.w;
    }
    { // B tile
      const int k = k0 + brow;
      #pragma unroll
      for (int h = 0; h < 2; h++) {
        const int n = n0 + bc0 + h * 64;
        float4 v = make_float4(0.f, 0.f, 0.f, 0.f);
        if (k < K) {
          if (n + 3 < N) {
            v = *(const float4*)(B + (size_t)k * N + n);
          } else {
            float tmp[4] = {0.f, 0.f, 0.f, 0.f};
            for (int j = 0; j < 4; j++) if (n + j < N) tmp[j] = B[(size_t)k * N + n + j];
            v = make_float4(tmp[0], tmp[1], tmp[2], tmp[3]);
          }
        }
        *(float4*)&Bs[brow][bc0 + h * 64] = v;
      }
    }
    __syncthreads();
    #pragma unroll
    for (int k = 0; k < BK; k++) {
      float a[4], b[8];
      *(float4*)&a[0] = *(const float4*)&As[k][tm0];
      *(float4*)&b[0] = *(const float4*)&Bs[k][tn0];
      *(float4*)&b[4] = *(const float4*)&Bs[k][tn0 + 4];
      #pragma unroll
      for (int i = 0; i < 4; i++)
        #pragma unroll
        for (int j = 0; j < 8; j++) acc[i][j] = fmaf(a[i], b[j], acc[i][j]);
    }
    __syncthreads();
  }
  #pragma unroll
  for (int i = 0; i < 4; i++) {
    const int r = m0 + tm0 + i;
    if (r >= M) continue;
    #pragma unroll
    for (int j = 0; j < 8; j++) {
      const int c = n0 + tn0 + j;
      if (c >= N) continue;
      float v = acc[i][j];
      if (HASBIAS) v += bias[c];
      if (RELU) v = fmaxf(v, 0.f);
      C[(size_t)r * N + c] = v;
    }
  }
}

// ---------------- counting-sort infrastructure
__global__ __launch_bounds__(256) void hist_k(const int* __restrict__ idx, int* __restrict__ hist, int n)
{
  int i = blockIdx.x * blockDim.x + threadIdx.x;
  if (i < n) atomicAdd(&hist[idx[i]], 1);
}

// single-block exclusive scan, base has n+1 entries
__global__ __launch_bounds__(256) void scan_k(const int* __restrict__ hist, int* __restrict__ base, int n)
{
  __shared__ int sums[256];
  const int t = threadIdx.x;
  const int chunk = (n + 255) / 256;
  const int lo = t * chunk;
  const int hi = min(lo + chunk, n);
  int s = 0;
  for (int i = lo; i < hi; i++) s += hist[i];
  sums[t] = s;
  __syncthreads();
  for (int off = 1; off < 256; off <<= 1) {
    int u = (t >= off) ? sums[t - off] : 0;
    __syncthreads();
    sums[t] += u;
    __syncthreads();
  }
  int run = sums[t] - s;  // exclusive prefix of this thread's chunk
  for (int i = lo; i < hi; i++) { base[i] = run; run += hist[i]; }
  if (hi == n) base[n] = run;
}

__global__ __launch_bounds__(256) void edge_scatter_k(
    const int* __restrict__ esrc, const int* __restrict__ edst, const float* __restrict__ ew,
    const int* __restrict__ bx, const int* __restrict__ bg,
    const int* __restrict__ ebase, int* __restrict__ ecur,
    float* __restrict__ s_w, int* __restrict__ s_src,
    int* __restrict__ s_en, int* __restrict__ s_gn)
{
  int e = blockIdx.x * blockDim.x + threadIdx.x;
  if (e >= NEDGE) return;
  int d = edst[e];
  int p = ebase[d] + atomicAdd(&ecur[d], 1);
  int s = esrc[e];
  s_w[p] = ew[e];
  s_src[p] = s;
  s_en[p] = bx[s];
  s_gn[p] = bg[s];
}

__global__ __launch_bounds__(256) void node_scatter_k(
    const int* __restrict__ bx, const int* __restrict__ nbase, int* __restrict__ ncur,
    int* __restrict__ node_of)
{
  int i = blockIdx.x * blockDim.x + threadIdx.x;
  if (i >= NNODE) return;
  int ent = bx[i];
  int p = nbase[ent] + atomicAdd(&ncur[ent], 1);
  node_of[p] = i;
}

// ---------------- GCN layer 1 gather: h1[d] = relu(sum_e w*(eg1[en]+rg1[gn]) + b_gc1), 256 cols
__global__ __launch_bounds__(256) void spmm1_g(
    const int* __restrict__ ebase, const float* __restrict__ s_w,
    const int* __restrict__ s_en, const int* __restrict__ s_gn,
    const float* __restrict__ eg1, const float* __restrict__ rg1,
    const float* __restrict__ b_g1, float* __restrict__ out)
{
  const int gid = blockIdx.x * blockDim.x + threadIdx.x;
  const int d = gid >> 6, lane = gid & 63;
  if (d >= NNODE) return;
  const int p0 = ebase[d], p1 = ebase[d + 1];
  float4 acc = make_float4(0.f, 0.f, 0.f, 0.f);
  for (int p = p0; p < p1; ++p) {
    const float w = s_w[p];
    const int en = s_en[p], gn = s_gn[p];
    const float4 v = ((const float4*)(eg1 + (size_t)en * 256))[lane];
    const float4 u = ((const float4*)(rg1 + (size_t)gn * 256))[lane];
    acc.x += w * (v.x + u.x); acc.y += w * (v.y + u.y);
    acc.z += w * (v.z + u.z); acc.w += w * (v.w + u.w);
  }
  const float4 b = ((const float4*)b_g1)[lane];
  acc.x = fmaxf(acc.x + b.x, 0.f); acc.y = fmaxf(acc.y + b.y, 0.f);
  acc.z = fmaxf(acc.z + b.z, 0.f); acc.w = fmaxf(acc.w + b.w, 0.f);
  ((float4*)(out + (size_t)d * 256))[lane] = acc;
}

// ---------------- GCN layer 2 gather + score fusion:
// h2[d] = sum_e w*hg2[src] + b_gc2 (200 cols); score[d] = dot(h2[d], W_e[0:200])
__global__ __launch_bounds__(256) void spmm2_g(
    const int* __restrict__ ebase, const float* __restrict__ s_w,
    const int* __restrict__ s_src, const float* __restrict__ hg2,
    const float* __restrict__ b_g2, const float* __restrict__ W_e,
    float* __restrict__ h2, float* __restrict__ score)
{
  const int gid = blockIdx.x * blockDim.x + threadIdx.x;
  const int d = gid >> 6, lane = gid & 63;
  if (d >= NNODE) return;
  const int p0 = ebase[d], p1 = ebase[d + 1];
  float4 acc = make_float4(0.f, 0.f, 0.f, 0.f);
  if (lane < 50) {
    for (int p = p0; p < p1; ++p) {
      const float w = s_w[p];
      const int s = s_src[p];
      const float4 v = ((const float4*)(hg2 + (size_t)s * 200))[lane];
      acc.x += w * v.x; acc.y += w * v.y; acc.z += w * v.z; acc.w += w * v.w;
    }
    const float4 b = ((const float4*)b_g2)[lane];
    acc.x += b.x; acc.y += b.y; acc.z += b.z; acc.w += b.w;
    ((float4*)(h2 + (size_t)d * 200))[lane] = acc;
  }
  // fused score = dot(h2 row, W_e[0:200]); segment-constant terms cancel in softmax
  float s = 0.f;
  if (lane < 50) {
    const float4 we = ((const float4*)W_e)[lane];
    s = acc.x * we.x + acc.y * we.y + acc.z * we.z + acc.w * we.w;
  }
  for (int off = 32; off; off >>= 1) s += __shfl_down(s, off);
  if (lane == 0) score[d] = s;
}

// ---------------- per-entity: softmax over segment + weighted sum + mean, no atomics
__global__ __launch_bounds__(256) void ent_k(
    const int* __restrict__ nbase, const int* __restrict__ node_of,
    const float* __restrict__ h2, const float* __restrict__ score,
    float* __restrict__ embE)
{
  const int gid = blockIdx.x * blockDim.x + threadIdx.x;
  const int ent = gid >> 6, lane = gid & 63;
  if (ent >= N_ENT) return;
  const int p0 = nbase[ent], p1 = nbase[ent + 1];
  const int cnt = p1 - p0;
  // segment max
  float m = -3.4e38f;
  for (int p = p0 + lane; p < p1; p += 64) m = fmaxf(m, score[node_of[p]]);
  #pragma unroll
  for (int off = 32; off; off >>= 1) m = fmaxf(m, __shfl_xor(m, off));
  // exp-sum
  float es = 0.f;
  for (int p = p0 + lane; p < p1; p += 64) es += __expf(score[node_of[p]] - m);
  #pragma unroll
  for (int off = 32; off; off >>= 1) es += __shfl_xor(es, off);
  const float inv_es = (cnt > 0) ? 1.f / es : 0.f;
  const float inv_cnt = 1.f / fmaxf((float)cnt, 1.f);
  // weighted sum (softmax) + plain sum (mean)
  float4 aw = make_float4(0.f, 0.f, 0.f, 0.f);
  float4 am = make_float4(0.f, 0.f, 0.f, 0.f);
  for (int p = p0; p < p1; ++p) {
    const int nd = node_of[p];
    const float z = __expf(score[nd] - m) * inv_es;
    if (lane < 50) {
      const float4 v = ((const float4*)(h2 + (size_t)nd * 200))[lane];
      aw.x += z * v.x; aw.y += z * v.y; aw.z += z * v.z; aw.w += z * v.w;
      am.x += v.x; am.y += v.y; am.z += v.z; am.w += v.w;
    }
  }
  if (lane < 50) {
    ((float4*)(embE + (size_t)ent * 400))[lane] = aw;
    float4 mn = make_float4(am.x * inv_cnt, am.y * inv_cnt, am.z * inv_cnt, am.w * inv_cnt);
    ((float4*)(embE + (size_t)ent * 400 + 200))[lane] = mn;
  }
}

extern "C" void kernel_launch(void* const* d_in, const int* in_sizes, int n_in,
                              void* d_out, int out_size, void* d_ws, size_t ws_size,
                              hipStream_t stream)
{
  const float* img  = (const float*)d_in[0];
  const float* txt  = (const float*)d_in[1];
  const float* rel  = (const float*)d_in[2];
  const float* W_it = (const float*)d_in[3];
  const float* b_it = (const float*)d_in[4];
  const float* W_ri = (const float*)d_in[5];
  const float* b_ri = (const float*)d_in[6];
  const float* W_g1 = (const float*)d_in[7];
  const float* b_g1 = (const float*)d_in[8];
  const float* W_g2 = (const float*)d_in[9];
  const float* b_g2 = (const float*)d_in[10];
  const float* W_e  = (const float*)d_in[11];
  const float* W_eo = (const float*)d_in[13];
  const float* b_eo = (const float*)d_in[14];
  const float* W_r  = (const float*)d_in[15];
  const float* b_r  = (const float*)d_in[16];
  const float* ew   = (const float*)d_in[17];
  const int*   bx   = (const int*)d_in[18];
  const int*   bg   = (const int*)d_in[19];
  const int*   esrc = (const int*)d_in[20];
  const int*   edst = (const int*)d_in[21];

  float* ws = (float*)d_ws;
  size_t off = 0;
  auto alloc = [&](size_t n){ size_t r = off; off += (n + 255) & ~(size_t)255; return r; };
  float* emf  = ws + alloc((size_t)N_ENT * 100);
  float* rin  = ws + alloc((size_t)N_REL * 100);
  float* eg1  = ws + alloc((size_t)N_ENT * 256);
  float* rg1  = ws + alloc((size_t)N_REL * 256);
  float* big1 = ws + alloc((size_t)NNODE * 256);   // h1; first NNODE*200 reused as h2
  float* hg2  = ws + alloc((size_t)NNODE * 200);
  float* embE = ws + alloc((size_t)N_ENT * 400);   // [:,0:200]=wsum, [:,200:400]=mean
  float* score = ws + alloc(NNODE);
  int* ehist = (int*)(ws + alloc(NNODE));
  int* ecur  = (int*)(ws + alloc(NNODE));
  int* ebase = (int*)(ws + alloc(NNODE + 1));
  int* nhist = (int*)(ws + alloc(N_ENT));
  int* ncur  = (int*)(ws + alloc(N_ENT));
  int* nbase = (int*)(ws + alloc(N_ENT + 1));
  float* s_w  = ws + alloc(NEDGE);
  int* s_src  = (int*)(ws + alloc(NEDGE));
  int* s_en   = (int*)(ws + alloc(NEDGE));
  int* s_gn   = (int*)(ws + alloc(NEDGE));
  int* node_of = (int*)(ws + alloc(NNODE));
  float* h2 = big1;

  dim3 blk(256);

  // ---- build CSRs (edges by dst, nodes by entity)
  hipMemsetAsync(ehist, 0, (size_t)NNODE * 4, stream);
  hipMemsetAsync(ecur,  0, (size_t)NNODE * 4, stream);
  hipMemsetAsync(nhist, 0, (size_t)N_ENT * 4, stream);
  hipMemsetAsync(ncur,  0, (size_t)N_ENT * 4, stream);
  hist_k<<<ceil_div(NEDGE, 256), blk, 0, stream>>>(edst, ehist, NEDGE);
  hist_k<<<ceil_div(NNODE, 256), blk, 0, stream>>>(bx, nhist, NNODE);
  scan_k<<<1, blk, 0, stream>>>(ehist, ebase, NNODE);
  scan_k<<<1, blk, 0, stream>>>(nhist, nbase, N_ENT);
  edge_scatter_k<<<ceil_div(NEDGE, 256), blk, 0, stream>>>(
      esrc, edst, ew, bx, bg, ebase, ecur, s_w, s_src, s_en, s_gn);
  node_scatter_k<<<ceil_div(NNODE, 256), blk, 0, stream>>>(bx, nbase, ncur, node_of);

  // ---- encoder GEMMs
  gemm_f32<false, true><<<dim3(1, ceil_div(N_ENT, 64)), blk, 0, stream>>>(
      img, 4096, txt, W_it, b_it, emf, N_ENT, 4396, 100);
  gemm_f32<true, true><<<dim3(1, ceil_div(N_REL, 64)), blk, 0, stream>>>(
      rel, 300, rel, W_ri, b_ri, rin, N_REL, 300, 100);
  gemm_f32<false, false><<<dim3(2, ceil_div(N_ENT, 64)), blk, 0, stream>>>(
      emf, 100, emf, W_g1, nullptr, eg1, N_ENT, 100, 256);
  gemm_f32<false, false><<<dim3(2, ceil_div(N_REL, 64)), blk, 0, stream>>>(
      rin, 100, rin, W_g1 + 100 * 256, nullptr, rg1, N_REL, 100, 256);

  // ---- GCN layer 1 (gather, fused bias+relu)
  spmm1_g<<<ceil_div(NNODE * 64, 256), blk, 0, stream>>>(
      ebase, s_w, s_en, s_gn, eg1, rg1, b_g1, big1);

  // ---- GCN layer 2: hg2 = h1 @ W_gc2; h2 = gather + bias; fused score
  gemm_f32<false, false><<<dim3(2, ceil_div(NNODE, 64)), blk, 0, stream>>>(
      big1, 256, big1, W_g2, nullptr, hg2, NNODE, 256, 200);
  spmm2_g<<<ceil_div(NNODE * 64, 256), blk, 0, stream>>>(
      ebase, s_w, s_src, hg2, b_g2, W_e, h2, score);

  // ---- per-entity softmax + weighted sum + mean
  ent_k<<<ceil_div(N_ENT * 64, 256), blk, 0, stream>>>(nbase, node_of, h2, score, embE);

  // ---- final projections
  float* out_new = (float*)d_out;
  float* out_rel = out_new + (size_t)N_ENT * 200;
  gemm_f32<false, true><<<dim3(2, ceil_div(N_ENT, 64)), blk, 0, stream>>>(
      embE, 400, embE, W_eo, b_eo, out_new, N_ENT, 400, 200);
  gemm_f32<true, true><<<dim3(2, ceil_div(N_REL, 64)), blk, 0, stream>>>(
      rel, 300, rel, W_r, b_r, out_rel, N_REL, 300, 200);
}

// Round 3
// 909.787 us; speedup vs baseline: 5.3305x; 1.7473x over previous
//
#include <hip/hip_runtime.h>

#define N_ENT 14951
#define N_REL 1345
#define NNODE 120000
#define NEDGE 480000
#define MP_ENC 14976   // 234*64
#define KP_ENC 4480    // 4*1120, covers 4396
#define NP_ENC 112

static inline int ceil_div(int a, int b){ return (a + b - 1) / b; }

typedef __bf16 bf16x8 __attribute__((ext_vector_type(8)));
typedef float f32x4 __attribute__((ext_vector_type(4)));

__device__ inline unsigned short f2bf(float f){
  unsigned u = __float_as_uint(f);
  return (unsigned short)((u + 0x7fffu + ((u >> 16) & 1u)) >> 16);
}

// ---------------- bf16 MFMA encoder GEMM with split-K:
// part[s][MP_ENC][112] = concat(img,txt)[:, krange(s)] @ W[kr(s), 0:112]
__global__ __launch_bounds__(256) void enc_mfma(
    const float* __restrict__ img, const float* __restrict__ txt,
    const unsigned short* __restrict__ Wt1, float* __restrict__ part)
{
  __shared__ unsigned short As[64 * 40];   // 64 rows x 32 k, stride 40 (2-way banks)
  __shared__ unsigned short Bs[112 * 40];  // 112 cols x 32 k
  const int t = threadIdx.x;
  const int m0 = blockIdx.x * 64;
  const int s = blockIdx.y;
  const int l = t & 63, w = t >> 6;
  f32x4 acc[7];
  #pragma unroll
  for (int i = 0; i < 7; i++) acc[i] = f32x4{0.f, 0.f, 0.f, 0.f};

  for (int step = 0; step < 35; ++step) {
    const int kb = s * 1120 + step * 32;
    #pragma unroll
    for (int p = 0; p < 2; ++p) {         // stage A: 64 rows x 8 float4-chunks
      const int c = t + p * 256;
      const int row = c >> 3, kq = c & 7;
      const int rowg = m0 + row;
      const int k = kb + kq * 4;
      float4 v = make_float4(0.f, 0.f, 0.f, 0.f);
      if (rowg < N_ENT) {
        if (k < 4096)      v = *(const float4*)(img + (size_t)rowg * 4096 + k);
        else if (k < 4396) v = *(const float4*)(txt + (size_t)rowg * 300 + (k - 4096));
      }
      ushort4 b;
      b.x = f2bf(v.x); b.y = f2bf(v.y); b.z = f2bf(v.z); b.w = f2bf(v.w);
      *(ushort4*)&As[row * 40 + kq * 4] = b;
    }
    {                                      // stage B: 112 rows x 4 16B-chunks
      const int n = t >> 2, k16 = t & 3;
      *(uint4*)&Bs[n * 40 + k16 * 8] = *(const uint4*)(Wt1 + (size_t)n * KP_ENC + kb + k16 * 8);
      if (t < 192) {
        const int c = t + 256;
        const int n2 = c >> 2, k2 = c & 3;
        *(uint4*)&Bs[n2 * 40 + k2 * 8] = *(const uint4*)(Wt1 + (size_t)n2 * KP_ENC + kb + k2 * 8);
      }
    }
    __syncthreads();
    bf16x8 a = *(const bf16x8*)&As[(w * 16 + (l & 15)) * 40 + (l >> 4) * 8];
    #pragma unroll
    for (int ct = 0; ct < 7; ++ct) {
      bf16x8 bb = *(const bf16x8*)&Bs[(ct * 16 + (l & 15)) * 40 + (l >> 4) * 8];
      acc[ct] = __builtin_amdgcn_mfma_f32_16x16x32_bf16(a, bb, acc[ct], 0, 0, 0);
    }
    __syncthreads();
  }
  const int rb = m0 + w * 16 + (l >> 4) * 4;
  const int col = l & 15;
  #pragma unroll
  for (int ct = 0; ct < 7; ++ct)
    #pragma unroll
    for (int i = 0; i < 4; ++i)
      part[((size_t)s * MP_ENC + rb + i) * NP_ENC + ct * 16 + col] = acc[ct][i];
}

__global__ __launch_bounds__(256) void enc_reduce(
    const float* __restrict__ part, const float* __restrict__ bias, float* __restrict__ emf)
{
  int i = blockIdx.x * 256 + threadIdx.x;
  if (i >= N_ENT * 100) return;
  int r = i / 100, c = i % 100;
  float v = bias[c];
  #pragma unroll
  for (int s = 0; s < 4; ++s) v += part[((size_t)s * MP_ENC + r) * NP_ENC + c];
  emf[(size_t)r * 100 + c] = v;
}

// ---------------- bf16 MFMA: hg2[120000][200] = h1[120000][256] @ W_gc2[256][200]
__global__ __launch_bounds__(256) void gemm2_mfma(
    const float* __restrict__ h1, const unsigned short* __restrict__ Wt2,
    float* __restrict__ hg2)
{
  __shared__ unsigned short As[64 * 40];
  __shared__ unsigned short Bs[208 * 40];
  const int t = threadIdx.x;
  const int m0 = blockIdx.x * 64;
  const int l = t & 63, w = t >> 6;
  f32x4 acc[13];
  #pragma unroll
  for (int i = 0; i < 13; i++) acc[i] = f32x4{0.f, 0.f, 0.f, 0.f};

  for (int step = 0; step < 8; ++step) {
    const int kb = step * 32;
    #pragma unroll
    for (int p = 0; p < 2; ++p) {
      const int c = t + p * 256;
      const int row = c >> 3, kq = c & 7;
      float4 v = *(const float4*)(h1 + (size_t)(m0 + row) * 256 + kb + kq * 4);
      ushort4 b;
      b.x = f2bf(v.x); b.y = f2bf(v.y); b.z = f2bf(v.z); b.w = f2bf(v.w);
      *(ushort4*)&As[row * 40 + kq * 4] = b;
    }
    #pragma unroll
    for (int p = 0; p < 4; ++p) {
      const int c = t + p * 256;
      if (c < 832) {
        const int n = c >> 2, k16 = c & 3;
        *(uint4*)&Bs[n * 40 + k16 * 8] = *(const uint4*)(Wt2 + (size_t)n * 256 + kb + k16 * 8);
      }
    }
    __syncthreads();
    bf16x8 a = *(const bf16x8*)&As[(w * 16 + (l & 15)) * 40 + (l >> 4) * 8];
    #pragma unroll
    for (int ct = 0; ct < 13; ++ct) {
      bf16x8 bb = *(const bf16x8*)&Bs[(ct * 16 + (l & 15)) * 40 + (l >> 4) * 8];
      acc[ct] = __builtin_amdgcn_mfma_f32_16x16x32_bf16(a, bb, acc[ct], 0, 0, 0);
    }
    __syncthreads();
  }
  const int rb = m0 + w * 16 + (l >> 4) * 4;
  const int col0 = l & 15;
  #pragma unroll
  for (int ct = 0; ct < 13; ++ct) {
    const int col = ct * 16 + col0;
    if (col < 200) {
      #pragma unroll
      for (int i = 0; i < 4; ++i)
        hg2[(size_t)(rb + i) * 200 + col] = acc[ct][i];
    }
  }
}

// ---------------- weight transpose+bf16 prep
__global__ __launch_bounds__(256) void wt1_k(const float* __restrict__ W, unsigned short* __restrict__ Wt)
{
  int n = blockIdx.y;
  int k = blockIdx.x * 256 + threadIdx.x;
  if (k >= KP_ENC) return;
  float v = (n < 100 && k < 4396) ? W[(size_t)k * 100 + n] : 0.f;
  Wt[(size_t)n * KP_ENC + k] = f2bf(v);
}
__global__ __launch_bounds__(256) void wt2_k(const float* __restrict__ W, unsigned short* __restrict__ Wt)
{
  int i = blockIdx.x * 256 + threadIdx.x;
  if (i >= 208 * 256) return;
  int n = i >> 8, k = i & 255;
  float v = (n < 200) ? W[(size_t)k * 200 + n] : 0.f;
  Wt[i] = f2bf(v);
}

// ---------------- generic f32 GEMM (small matrices): C = concat(A1,A2) @ B (+bias)(+relu)
template<bool RELU, bool HASBIAS>
__global__ __launch_bounds__(256) void gemm_f32(
    const float* __restrict__ A1, int K1, const float* __restrict__ A2,
    const float* __restrict__ B, const float* __restrict__ bias,
    float* __restrict__ C, int M, int K, int N)
{
  constexpr int BM = 64, BN = 128, BK = 16;
  __shared__ float As[BK][BM + 4];
  __shared__ float Bs[BK][BN];
  const int t = threadIdx.x;
  const int m0 = blockIdx.y * BM, n0 = blockIdx.x * BN;
  const int tr = t >> 4, tc = t & 15;
  const int tm0 = tr * 4, tn0 = tc * 8;
  const int K2 = K - K1;
  const int arow = t >> 2, aq = (t & 3) * 4;
  const int brow = t >> 4, bc0 = (t & 15) * 4;
  float acc[4][8];
  #pragma unroll
  for (int i = 0; i < 4; i++)
    #pragma unroll
    for (int j = 0; j < 8; j++) acc[i][j] = 0.f;

  for (int k0 = 0; k0 < K; k0 += BK) {
    {
      const int r = m0 + arow;
      const int k = k0 + aq;
      float4 v = make_float4(0.f, 0.f, 0.f, 0.f);
      if (r < M) {
        if (k + 3 < K1) {
          v = *(const float4*)(A1 + (size_t)r * K1 + k);
        } else if (k >= K1 && (k - K1) + 3 < K2) {
          v = *(const float4*)(A2 + (size_t)r * K2 + (k - K1));
        } else {
          float tmp[4] = {0.f, 0.f, 0.f, 0.f};
          #pragma unroll
          for (int j = 0; j < 4; j++) {
            int kj = k + j;
            if (kj < K) tmp[j] = (kj < K1) ? A1[(size_t)r * K1 + kj]
                                           : A2[(size_t)r * K2 + (kj - K1)];
          }
          v = make_float4(tmp[0], tmp[1], tmp[2], tmp[3]);
        }
      }
      As[aq + 0][arow] = v.x; As[aq + 1][arow] = v.y;
      As[aq + 2][arow] = v.z; As[aq + 3][arow] = v.w;
    }
    {
      const int k = k0 + brow;
      #pragma unroll
      for (int h = 0; h < 2; h++) {
        const int n = n0 + bc0 + h * 64;
        float4 v = make_float4(0.f, 0.f, 0.f, 0.f);
        if (k < K) {
          if (n + 3 < N) {
            v = *(const float4*)(B + (size_t)k * N + n);
          } else {
            float tmp[4] = {0.f, 0.f, 0.f, 0.f};
            for (int j = 0; j < 4; j++) if (n + j < N) tmp[j] = B[(size_t)k * N + n + j];
            v = make_float4(tmp[0], tmp[1], tmp[2], tmp[3]);
          }
        }
        *(float4*)&Bs[brow][bc0 + h * 64] = v;
      }
    }
    __syncthreads();
    #pragma unroll
    for (int k = 0; k < BK; k++) {
      float a[4], b[8];
      *(float4*)&a[0] = *(const float4*)&As[k][tm0];
      *(float4*)&b[0] = *(const float4*)&Bs[k][tn0];
      *(float4*)&b[4] = *(const float4*)&Bs[k][tn0 + 4];
      #pragma unroll
      for (int i = 0; i < 4; i++)
        #pragma unroll
        for (int j = 0; j < 8; j++) acc[i][j] = fmaf(a[i], b[j], acc[i][j]);
    }
    __syncthreads();
  }
  #pragma unroll
  for (int i = 0; i < 4; i++) {
    const int r = m0 + tm0 + i;
    if (r >= M) continue;
    #pragma unroll
    for (int j = 0; j < 8; j++) {
      const int c = n0 + tn0 + j;
      if (c >= N) continue;
      float v = acc[i][j];
      if (HASBIAS) v += bias[c];
      if (RELU) v = fmaxf(v, 0.f);
      C[(size_t)r * N + c] = v;
    }
  }
}

// ---------------- counting-sort infrastructure
__global__ __launch_bounds__(256) void hist_k(const int* __restrict__ idx, int* __restrict__ hist, int n)
{
  int i = blockIdx.x * blockDim.x + threadIdx.x;
  if (i < n) atomicAdd(&hist[idx[i]], 1);
}

__global__ __launch_bounds__(256) void scan_k(const int* __restrict__ hist, int* __restrict__ base, int n)
{
  __shared__ int sums[256];
  const int t = threadIdx.x;
  const int chunk = (n + 255) / 256;
  const int lo = t * chunk;
  const int hi = min(lo + chunk, n);
  int s = 0;
  for (int i = lo; i < hi; i++) s += hist[i];
  sums[t] = s;
  __syncthreads();
  for (int off = 1; off < 256; off <<= 1) {
    int u = (t >= off) ? sums[t - off] : 0;
    __syncthreads();
    sums[t] += u;
    __syncthreads();
  }
  int run = sums[t] - s;
  for (int i = lo; i < hi; i++) { base[i] = run; run += hist[i]; }
  if (hi == n) base[n] = run;
}

__global__ __launch_bounds__(256) void edge_scatter_k(
    const int* __restrict__ esrc, const int* __restrict__ edst, const float* __restrict__ ew,
    const int* __restrict__ bx, const int* __restrict__ bg,
    const int* __restrict__ ebase, int* __restrict__ ecur,
    float* __restrict__ s_w, int* __restrict__ s_src,
    int* __restrict__ s_en, int* __restrict__ s_gn)
{
  int e = blockIdx.x * blockDim.x + threadIdx.x;
  if (e >= NEDGE) return;
  int d = edst[e];
  int p = ebase[d] + atomicAdd(&ecur[d], 1);
  int s = esrc[e];
  s_w[p] = ew[e];
  s_src[p] = s;
  s_en[p] = bx[s];
  s_gn[p] = bg[s];
}

__global__ __launch_bounds__(256) void node_scatter_k(
    const int* __restrict__ bx, const int* __restrict__ nbase, int* __restrict__ ncur,
    int* __restrict__ node_of)
{
  int i = blockIdx.x * blockDim.x + threadIdx.x;
  if (i >= NNODE) return;
  int ent = bx[i];
  int p = nbase[ent] + atomicAdd(&ncur[ent], 1);
  node_of[p] = i;
}

// ---------------- GCN layer 1 gather
__global__ __launch_bounds__(256) void spmm1_g(
    const int* __restrict__ ebase, const float* __restrict__ s_w,
    const int* __restrict__ s_en, const int* __restrict__ s_gn,
    const float* __restrict__ eg1, const float* __restrict__ rg1,
    const float* __restrict__ b_g1, float* __restrict__ out)
{
  const int gid = blockIdx.x * blockDim.x + threadIdx.x;
  const int d = gid >> 6, lane = gid & 63;
  if (d >= NNODE) return;
  const int p0 = ebase[d], p1 = ebase[d + 1];
  float4 acc = make_float4(0.f, 0.f, 0.f, 0.f);
  for (int p = p0; p < p1; ++p) {
    const float w = s_w[p];
    const int en = s_en[p], gn = s_gn[p];
    const float4 v = ((const float4*)(eg1 + (size_t)en * 256))[lane];
    const float4 u = ((const float4*)(rg1 + (size_t)gn * 256))[lane];
    acc.x += w * (v.x + u.x); acc.y += w * (v.y + u.y);
    acc.z += w * (v.z + u.z); acc.w += w * (v.w + u.w);
  }
  const float4 b = ((const float4*)b_g1)[lane];
  acc.x = fmaxf(acc.x + b.x, 0.f); acc.y = fmaxf(acc.y + b.y, 0.f);
  acc.z = fmaxf(acc.z + b.z, 0.f); acc.w = fmaxf(acc.w + b.w, 0.f);
  ((float4*)(out + (size_t)d * 256))[lane] = acc;
}

// ---------------- GCN layer 2 gather + fused score
__global__ __launch_bounds__(256) void spmm2_g(
    const int* __restrict__ ebase, const float* __restrict__ s_w,
    const int* __restrict__ s_src, const float* __restrict__ hg2,
    const float* __restrict__ b_g2, const float* __restrict__ W_e,
    float* __restrict__ h2, float* __restrict__ score)
{
  const int gid = blockIdx.x * blockDim.x + threadIdx.x;
  const int d = gid >> 6, lane = gid & 63;
  if (d >= NNODE) return;
  const int p0 = ebase[d], p1 = ebase[d + 1];
  float4 acc = make_float4(0.f, 0.f, 0.f, 0.f);
  if (lane < 50) {
    for (int p = p0; p < p1; ++p) {
      const float w = s_w[p];
      const int s = s_src[p];
      const float4 v = ((const float4*)(hg2 + (size_t)s * 200))[lane];
      acc.x += w * v.x; acc.y += w * v.y; acc.z += w * v.z; acc.w += w * v.w;
    }
    const float4 b = ((const float4*)b_g2)[lane];
    acc.x += b.x; acc.y += b.y; acc.z += b.z; acc.w += b.w;
    ((float4*)(h2 + (size_t)d * 200))[lane] = acc;
  }
  float s = 0.f;
  if (lane < 50) {
    const float4 we = ((const float4*)W_e)[lane];
    s = acc.x * we.x + acc.y * we.y + acc.z * we.z + acc.w * we.w;
  }
  for (int off = 32; off; off >>= 1) s += __shfl_down(s, off);
  if (lane == 0) score[d] = s;
}

// ---------------- per-entity softmax + weighted sum + mean
__global__ __launch_bounds__(256) void ent_k(
    const int* __restrict__ nbase, const int* __restrict__ node_of,
    const float* __restrict__ h2, const float* __restrict__ score,
    float* __restrict__ embE)
{
  const int gid = blockIdx.x * blockDim.x + threadIdx.x;
  const int ent = gid >> 6, lane = gid & 63;
  if (ent >= N_ENT) return;
  const int p0 = nbase[ent], p1 = nbase[ent + 1];
  const int cnt = p1 - p0;
  float m = -3.4e38f;
  for (int p = p0 + lane; p < p1; p += 64) m = fmaxf(m, score[node_of[p]]);
  #pragma unroll
  for (int off = 32; off; off >>= 1) m = fmaxf(m, __shfl_xor(m, off));
  float es = 0.f;
  for (int p = p0 + lane; p < p1; p += 64) es += __expf(score[node_of[p]] - m);
  #pragma unroll
  for (int off = 32; off; off >>= 1) es += __shfl_xor(es, off);
  const float inv_es = (cnt > 0) ? 1.f / es : 0.f;
  const float inv_cnt = 1.f / fmaxf((float)cnt, 1.f);
  float4 aw = make_float4(0.f, 0.f, 0.f, 0.f);
  float4 am = make_float4(0.f, 0.f, 0.f, 0.f);
  for (int p = p0; p < p1; ++p) {
    const int nd = node_of[p];
    const float z = __expf(score[nd] - m) * inv_es;
    if (lane < 50) {
      const float4 v = ((const float4*)(h2 + (size_t)nd * 200))[lane];
      aw.x += z * v.x; aw.y += z * v.y; aw.z += z * v.z; aw.w += z * v.w;
      am.x += v.x; am.y += v.y; am.z += v.z; am.w += v.w;
    }
  }
  if (lane < 50) {
    ((float4*)(embE + (size_t)ent * 400))[lane] = aw;
    float4 mn = make_float4(am.x * inv_cnt, am.y * inv_cnt, am.z * inv_cnt, am.w * inv_cnt);
    ((float4*)(embE + (size_t)ent * 400 + 200))[lane] = mn;
  }
}

extern "C" void kernel_launch(void* const* d_in, const int* in_sizes, int n_in,
                              void* d_out, int out_size, void* d_ws, size_t ws_size,
                              hipStream_t stream)
{
  const float* img  = (const float*)d_in[0];
  const float* txt  = (const float*)d_in[1];
  const float* rel  = (const float*)d_in[2];
  const float* W_it = (const float*)d_in[3];
  const float* b_it = (const float*)d_in[4];
  const float* W_ri = (const float*)d_in[5];
  const float* b_ri = (const float*)d_in[6];
  const float* W_g1 = (const float*)d_in[7];
  const float* b_g1 = (const float*)d_in[8];
  const float* W_g2 = (const float*)d_in[9];
  const float* b_g2 = (const float*)d_in[10];
  const float* W_e  = (const float*)d_in[11];
  const float* W_eo = (const float*)d_in[13];
  const float* b_eo = (const float*)d_in[14];
  const float* W_r  = (const float*)d_in[15];
  const float* b_r  = (const float*)d_in[16];
  const float* ew   = (const float*)d_in[17];
  const int*   bx   = (const int*)d_in[18];
  const int*   bg   = (const int*)d_in[19];
  const int*   esrc = (const int*)d_in[20];
  const int*   edst = (const int*)d_in[21];

  float* ws = (float*)d_ws;
  size_t off = 0;
  auto alloc = [&](size_t n){ size_t r = off; off += (n + 255) & ~(size_t)255; return r; };
  float* emf  = ws + alloc((size_t)N_ENT * 100);
  float* rin  = ws + alloc((size_t)N_REL * 100);
  float* eg1  = ws + alloc((size_t)N_ENT * 256);
  float* rg1  = ws + alloc((size_t)N_REL * 256);
  float* big1 = ws + alloc((size_t)NNODE * 256);   // h1; first NNODE*200 reused as h2
  float* hg2  = ws + alloc((size_t)NNODE * 200);   // also aliases enc split-K partials
  float* embE = ws + alloc((size_t)N_ENT * 400);
  float* score = ws + alloc(NNODE);
  int* ehist = (int*)(ws + alloc(NNODE));
  int* ecur  = (int*)(ws + alloc(NNODE));
  int* ebase = (int*)(ws + alloc(NNODE + 1));
  int* nhist = (int*)(ws + alloc(N_ENT));
  int* ncur  = (int*)(ws + alloc(N_ENT));
  int* nbase = (int*)(ws + alloc(N_ENT + 1));
  float* s_w  = ws + alloc(NEDGE);
  int* s_src  = (int*)(ws + alloc(NEDGE));
  int* s_en   = (int*)(ws + alloc(NEDGE));
  int* s_gn   = (int*)(ws + alloc(NEDGE));
  int* node_of = (int*)(ws + alloc(NNODE));
  unsigned short* Wt1 = (unsigned short*)(ws + alloc((size_t)NP_ENC * KP_ENC / 2));
  unsigned short* Wt2 = (unsigned short*)(ws + alloc((size_t)208 * 256 / 2));
  float* part = hg2;   // 4*14976*112 = 6.7M floats <= NNODE*200, used before hg2
  float* h2 = big1;

  dim3 blk(256);

  // ---- CSR builds
  hipMemsetAsync(ehist, 0, (size_t)NNODE * 4, stream);
  hipMemsetAsync(ecur,  0, (size_t)NNODE * 4, stream);
  hipMemsetAsync(nhist, 0, (size_t)N_ENT * 4, stream);
  hipMemsetAsync(ncur,  0, (size_t)N_ENT * 4, stream);
  hist_k<<<ceil_div(NEDGE, 256), blk, 0, stream>>>(edst, ehist, NEDGE);
  hist_k<<<ceil_div(NNODE, 256), blk, 0, stream>>>(bx, nhist, NNODE);
  scan_k<<<1, blk, 0, stream>>>(ehist, ebase, NNODE);
  scan_k<<<1, blk, 0, stream>>>(nhist, nbase, N_ENT);
  edge_scatter_k<<<ceil_div(NEDGE, 256), blk, 0, stream>>>(
      esrc, edst, ew, bx, bg, ebase, ecur, s_w, s_src, s_en, s_gn);
  node_scatter_k<<<ceil_div(NNODE, 256), blk, 0, stream>>>(bx, nbase, ncur, node_of);

  // ---- weight prep (bf16 transposed)
  wt1_k<<<dim3(ceil_div(KP_ENC, 256), NP_ENC), blk, 0, stream>>>(W_it, Wt1);
  wt2_k<<<ceil_div(208 * 256, 256), blk, 0, stream>>>(W_g2, Wt2);

  // ---- encoder: MFMA split-K + reduce
  enc_mfma<<<dim3(MP_ENC / 64, 4), blk, 0, stream>>>(img, txt, Wt1, part);
  enc_reduce<<<ceil_div(N_ENT * 100, 256), blk, 0, stream>>>(part, b_it, emf);

  // ---- small f32 GEMMs
  gemm_f32<true, true><<<dim3(1, ceil_div(N_REL, 64)), blk, 0, stream>>>(
      rel, 300, rel, W_ri, b_ri, rin, N_REL, 300, 100);
  gemm_f32<false, false><<<dim3(2, ceil_div(N_ENT, 64)), blk, 0, stream>>>(
      emf, 100, emf, W_g1, nullptr, eg1, N_ENT, 100, 256);
  gemm_f32<false, false><<<dim3(2, ceil_div(N_REL, 64)), blk, 0, stream>>>(
      rin, 100, rin, W_g1 + 100 * 256, nullptr, rg1, N_REL, 100, 256);

  // ---- GCN layer 1 (gather, fused bias+relu)
  spmm1_g<<<ceil_div(NNODE * 64, 256), blk, 0, stream>>>(
      ebase, s_w, s_en, s_gn, eg1, rg1, b_g1, big1);

  // ---- GCN layer 2: MFMA GEMM then gather + fused score
  gemm2_mfma<<<NNODE / 64, blk, 0, stream>>>(big1, Wt2, hg2);
  spmm2_g<<<ceil_div(NNODE * 64, 256), blk, 0, stream>>>(
      ebase, s_w, s_src, hg2, b_g2, W_e, h2, score);

  // ---- per-entity softmax + weighted sum + mean
  ent_k<<<ceil_div(N_ENT * 64, 256), blk, 0, stream>>>(nbase, node_of, h2, score, embE);

  // ---- final projections
  float* out_new = (float*)d_out;
  float* out_rel = out_new + (size_t)N_ENT * 200;
  gemm_f32<false, true><<<dim3(2, ceil_div(N_ENT, 64)), blk, 0, stream>>>(
      embE, 400, embE, W_eo, b_eo, out_new, N_ENT, 400, 200);
  gemm_f32<true, true><<<dim3(2, ceil_div(N_REL, 64)), blk, 0, stream>>>(
      rel, 300, rel, W_r, b_r, out_rel, N_REL, 300, 200);
}

// Round 4
// 706.568 us; speedup vs baseline: 6.8636x; 1.2876x over previous
//
#include <hip/hip_runtime.h>

#define N_ENT 14951
#define N_REL 1345
#define NNODE 120000
#define NEDGE 480000
#define MP_ENC 14976   // 234*64
#define KP_ENC 4480    // 4*1120, covers 4396
#define NP_ENC 112

static inline int ceil_div(int a, int b){ return (a + b - 1) / b; }

typedef __bf16 bf16x8 __attribute__((ext_vector_type(8)));
typedef float f32x4 __attribute__((ext_vector_type(4)));

__device__ inline unsigned short f2bf(float f){
  unsigned u = __float_as_uint(f);
  return (unsigned short)((u + 0x7fffu + ((u >> 16) & 1u)) >> 16);
}

// ---------------- bf16 MFMA encoder GEMM with split-K
__global__ __launch_bounds__(256) void enc_mfma(
    const float* __restrict__ img, const float* __restrict__ txt,
    const unsigned short* __restrict__ Wt1, float* __restrict__ part)
{
  __shared__ unsigned short As[64 * 40];
  __shared__ unsigned short Bs[112 * 40];
  const int t = threadIdx.x;
  const int m0 = blockIdx.x * 64;
  const int s = blockIdx.y;
  const int l = t & 63, w = t >> 6;
  f32x4 acc[7];
  #pragma unroll
  for (int i = 0; i < 7; i++) acc[i] = f32x4{0.f, 0.f, 0.f, 0.f};

  for (int step = 0; step < 35; ++step) {
    const int kb = s * 1120 + step * 32;
    #pragma unroll
    for (int p = 0; p < 2; ++p) {
      const int c = t + p * 256;
      const int row = c >> 3, kq = c & 7;
      const int rowg = m0 + row;
      const int k = kb + kq * 4;
      float4 v = make_float4(0.f, 0.f, 0.f, 0.f);
      if (rowg < N_ENT) {
        if (k < 4096)      v = *(const float4*)(img + (size_t)rowg * 4096 + k);
        else if (k < 4396) v = *(const float4*)(txt + (size_t)rowg * 300 + (k - 4096));
      }
      ushort4 b;
      b.x = f2bf(v.x); b.y = f2bf(v.y); b.z = f2bf(v.z); b.w = f2bf(v.w);
      *(ushort4*)&As[row * 40 + kq * 4] = b;
    }
    {
      const int n = t >> 2, k16 = t & 3;
      *(uint4*)&Bs[n * 40 + k16 * 8] = *(const uint4*)(Wt1 + (size_t)n * KP_ENC + kb + k16 * 8);
      if (t < 192) {
        const int c = t + 256;
        const int n2 = c >> 2, k2 = c & 3;
        *(uint4*)&Bs[n2 * 40 + k2 * 8] = *(const uint4*)(Wt1 + (size_t)n2 * KP_ENC + kb + k2 * 8);
      }
    }
    __syncthreads();
    bf16x8 a = *(const bf16x8*)&As[(w * 16 + (l & 15)) * 40 + (l >> 4) * 8];
    #pragma unroll
    for (int ct = 0; ct < 7; ++ct) {
      bf16x8 bb = *(const bf16x8*)&Bs[(ct * 16 + (l & 15)) * 40 + (l >> 4) * 8];
      acc[ct] = __builtin_amdgcn_mfma_f32_16x16x32_bf16(a, bb, acc[ct], 0, 0, 0);
    }
    __syncthreads();
  }
  const int rb = m0 + w * 16 + (l >> 4) * 4;
  const int col = l & 15;
  #pragma unroll
  for (int ct = 0; ct < 7; ++ct)
    #pragma unroll
    for (int i = 0; i < 4; ++i)
      part[((size_t)s * MP_ENC + rb + i) * NP_ENC + ct * 16 + col] = acc[ct][i];
}

__global__ __launch_bounds__(256) void enc_reduce(
    const float* __restrict__ part, const float* __restrict__ bias, float* __restrict__ emf)
{
  int i = blockIdx.x * 256 + threadIdx.x;
  if (i >= N_ENT * 100) return;
  int r = i / 100, c = i % 100;
  float v = bias[c];
  #pragma unroll
  for (int s = 0; s < 4; ++s) v += part[((size_t)s * MP_ENC + r) * NP_ENC + c];
  emf[(size_t)r * 100 + c] = v;
}

// ---------------- bf16 MFMA: hg2 = h1 @ W_gc2
__global__ __launch_bounds__(256) void gemm2_mfma(
    const float* __restrict__ h1, const unsigned short* __restrict__ Wt2,
    float* __restrict__ hg2)
{
  __shared__ unsigned short As[64 * 40];
  __shared__ unsigned short Bs[208 * 40];
  const int t = threadIdx.x;
  const int m0 = blockIdx.x * 64;
  const int l = t & 63, w = t >> 6;
  f32x4 acc[13];
  #pragma unroll
  for (int i = 0; i < 13; i++) acc[i] = f32x4{0.f, 0.f, 0.f, 0.f};

  for (int step = 0; step < 8; ++step) {
    const int kb = step * 32;
    #pragma unroll
    for (int p = 0; p < 2; ++p) {
      const int c = t + p * 256;
      const int row = c >> 3, kq = c & 7;
      float4 v = *(const float4*)(h1 + (size_t)(m0 + row) * 256 + kb + kq * 4);
      ushort4 b;
      b.x = f2bf(v.x); b.y = f2bf(v.y); b.z = f2bf(v.z); b.w = f2bf(v.w);
      *(ushort4*)&As[row * 40 + kq * 4] = b;
    }
    #pragma unroll
    for (int p = 0; p < 4; ++p) {
      const int c = t + p * 256;
      if (c < 832) {
        const int n = c >> 2, k16 = c & 3;
        *(uint4*)&Bs[n * 40 + k16 * 8] = *(const uint4*)(Wt2 + (size_t)n * 256 + kb + k16 * 8);
      }
    }
    __syncthreads();
    bf16x8 a = *(const bf16x8*)&As[(w * 16 + (l & 15)) * 40 + (l >> 4) * 8];
    #pragma unroll
    for (int ct = 0; ct < 13; ++ct) {
      bf16x8 bb = *(const bf16x8*)&Bs[(ct * 16 + (l & 15)) * 40 + (l >> 4) * 8];
      acc[ct] = __builtin_amdgcn_mfma_f32_16x16x32_bf16(a, bb, acc[ct], 0, 0, 0);
    }
    __syncthreads();
  }
  const int rb = m0 + w * 16 + (l >> 4) * 4;
  const int col0 = l & 15;
  #pragma unroll
  for (int ct = 0; ct < 13; ++ct) {
    const int col = ct * 16 + col0;
    if (col < 200) {
      #pragma unroll
      for (int i = 0; i < 4; ++i)
        hg2[(size_t)(rb + i) * 200 + col] = acc[ct][i];
    }
  }
}

// ---------------- weight transpose+bf16 prep
__global__ __launch_bounds__(256) void wt1_k(const float* __restrict__ W, unsigned short* __restrict__ Wt)
{
  int n = blockIdx.y;
  int k = blockIdx.x * 256 + threadIdx.x;
  if (k >= KP_ENC) return;
  float v = (n < 100 && k < 4396) ? W[(size_t)k * 100 + n] : 0.f;
  Wt[(size_t)n * KP_ENC + k] = f2bf(v);
}
__global__ __launch_bounds__(256) void wt2_k(const float* __restrict__ W, unsigned short* __restrict__ Wt)
{
  int i = blockIdx.x * 256 + threadIdx.x;
  if (i >= 208 * 256) return;
  int n = i >> 8, k = i & 255;
  float v = (n < 200) ? W[(size_t)k * 200 + n] : 0.f;
  Wt[i] = f2bf(v);
}

// ---------------- generic f32 GEMM (small matrices)
template<bool RELU, bool HASBIAS>
__global__ __launch_bounds__(256) void gemm_f32(
    const float* __restrict__ A1, int K1, const float* __restrict__ A2,
    const float* __restrict__ B, const float* __restrict__ bias,
    float* __restrict__ C, int M, int K, int N)
{
  constexpr int BM = 64, BN = 128, BK = 16;
  __shared__ float As[BK][BM + 4];
  __shared__ float Bs[BK][BN];
  const int t = threadIdx.x;
  const int m0 = blockIdx.y * BM, n0 = blockIdx.x * BN;
  const int tr = t >> 4, tc = t & 15;
  const int tm0 = tr * 4, tn0 = tc * 8;
  const int K2 = K - K1;
  const int arow = t >> 2, aq = (t & 3) * 4;
  const int brow = t >> 4, bc0 = (t & 15) * 4;
  float acc[4][8];
  #pragma unroll
  for (int i = 0; i < 4; i++)
    #pragma unroll
    for (int j = 0; j < 8; j++) acc[i][j] = 0.f;

  for (int k0 = 0; k0 < K; k0 += BK) {
    {
      const int r = m0 + arow;
      const int k = k0 + aq;
      float4 v = make_float4(0.f, 0.f, 0.f, 0.f);
      if (r < M) {
        if (k + 3 < K1) {
          v = *(const float4*)(A1 + (size_t)r * K1 + k);
        } else if (k >= K1 && (k - K1) + 3 < K2) {
          v = *(const float4*)(A2 + (size_t)r * K2 + (k - K1));
        } else {
          float tmp[4] = {0.f, 0.f, 0.f, 0.f};
          #pragma unroll
          for (int j = 0; j < 4; j++) {
            int kj = k + j;
            if (kj < K) tmp[j] = (kj < K1) ? A1[(size_t)r * K1 + kj]
                                           : A2[(size_t)r * K2 + (kj - K1)];
          }
          v = make_float4(tmp[0], tmp[1], tmp[2], tmp[3]);
        }
      }
      As[aq + 0][arow] = v.x; As[aq + 1][arow] = v.y;
      As[aq + 2][arow] = v.z; As[aq + 3][arow] = v.w;
    }
    {
      const int k = k0 + brow;
      #pragma unroll
      for (int h = 0; h < 2; h++) {
        const int n = n0 + bc0 + h * 64;
        float4 v = make_float4(0.f, 0.f, 0.f, 0.f);
        if (k < K) {
          if (n + 3 < N) {
            v = *(const float4*)(B + (size_t)k * N + n);
          } else {
            float tmp[4] = {0.f, 0.f, 0.f, 0.f};
            for (int j = 0; j < 4; j++) if (n + j < N) tmp[j] = B[(size_t)k * N + n + j];
            v = make_float4(tmp[0], tmp[1], tmp[2], tmp[3]);
          }
        }
        *(float4*)&Bs[brow][bc0 + h * 64] = v;
      }
    }
    __syncthreads();
    #pragma unroll
    for (int k = 0; k < BK; k++) {
      float a[4], b[8];
      *(float4*)&a[0] = *(const float4*)&As[k][tm0];
      *(float4*)&b[0] = *(const float4*)&Bs[k][tn0];
      *(float4*)&b[4] = *(const float4*)&Bs[k][tn0 + 4];
      #pragma unroll
      for (int i = 0; i < 4; i++)
        #pragma unroll
        for (int j = 0; j < 8; j++) acc[i][j] = fmaf(a[i], b[j], acc[i][j]);
    }
    __syncthreads();
  }
  #pragma unroll
  for (int i = 0; i < 4; i++) {
    const int r = m0 + tm0 + i;
    if (r >= M) continue;
    #pragma unroll
    for (int j = 0; j < 8; j++) {
      const int c = n0 + tn0 + j;
      if (c >= N) continue;
      float v = acc[i][j];
      if (HASBIAS) v += bias[c];
      if (RELU) v = fmaxf(v, 0.f);
      C[(size_t)r * N + c] = v;
    }
  }
}

// ---------------- counting-sort infrastructure
__global__ __launch_bounds__(256) void hist_k(const int* __restrict__ idx, int* __restrict__ hist, int n)
{
  int i = blockIdx.x * blockDim.x + threadIdx.x;
  if (i < n) atomicAdd(&hist[idx[i]], 1);
}

// ---- 3-phase parallel exclusive scan: base[0..n] from hist[0..n-1]
// phase 1: each block scans a 1024-elem chunk, writes per-elem exclusive (local) + chunk total
__global__ __launch_bounds__(256) void scan1_k(const int* __restrict__ hist, int* __restrict__ base,
                                               int* __restrict__ partial, int n)
{
  __shared__ int s[256];
  const int t = threadIdx.x;
  const int i0 = blockIdx.x * 1024 + t * 4;
  int v[4];
  #pragma unroll
  for (int j = 0; j < 4; j++) v[j] = (i0 + j < n) ? hist[i0 + j] : 0;
  const int tsum = v[0] + v[1] + v[2] + v[3];
  s[t] = tsum;
  __syncthreads();
  #pragma unroll
  for (int off = 1; off < 256; off <<= 1) {
    int u = (t >= off) ? s[t - off] : 0;
    __syncthreads();
    s[t] += u;
    __syncthreads();
  }
  int run = s[t] - tsum;
  #pragma unroll
  for (int j = 0; j < 4; j++) {
    if (i0 + j < n) base[i0 + j] = run;
    run += v[j];
  }
  if (t == 255) partial[blockIdx.x] = s[255];
}

// phase 2: single block exclusive-scans chunk totals (nb <= 256), writes grand total to base[n]
__global__ __launch_bounds__(256) void scan2_k(int* __restrict__ partial, int nb, int* __restrict__ total_dst)
{
  __shared__ int s[256];
  const int t = threadIdx.x;
  const int v = (t < nb) ? partial[t] : 0;
  s[t] = v;
  __syncthreads();
  #pragma unroll
  for (int off = 1; off < 256; off <<= 1) {
    int u = (t >= off) ? s[t - off] : 0;
    __syncthreads();
    s[t] += u;
    __syncthreads();
  }
  if (t < nb) partial[t] = s[t] - v;
  if (t == 255) *total_dst = s[255];
}

// phase 3: add chunk offsets
__global__ __launch_bounds__(256) void scan3_k(int* __restrict__ base, const int* __restrict__ partial, int n)
{
  int i = blockIdx.x * 256 + threadIdx.x;
  if (i < n) base[i] += partial[blockIdx.x >> 2];
}

__global__ __launch_bounds__(256) void edge_scatter_k(
    const int* __restrict__ esrc, const int* __restrict__ edst, const float* __restrict__ ew,
    const int* __restrict__ bx, const int* __restrict__ bg,
    const int* __restrict__ ebase, int* __restrict__ ecur,
    float* __restrict__ s_w, int* __restrict__ s_src,
    int* __restrict__ s_en, int* __restrict__ s_gn)
{
  int e = blockIdx.x * blockDim.x + threadIdx.x;
  if (e >= NEDGE) return;
  int d = edst[e];
  int p = ebase[d] + atomicAdd(&ecur[d], 1);
  int s = esrc[e];
  s_w[p] = ew[e];
  s_src[p] = s;
  s_en[p] = bx[s];
  s_gn[p] = bg[s];
}

__global__ __launch_bounds__(256) void node_scatter_k(
    const int* __restrict__ bx, const int* __restrict__ nbase, int* __restrict__ ncur,
    int* __restrict__ node_of)
{
  int i = blockIdx.x * blockDim.x + threadIdx.x;
  if (i >= NNODE) return;
  int ent = bx[i];
  int p = nbase[ent] + atomicAdd(&ncur[ent], 1);
  node_of[p] = i;
}

// ---------------- GCN layer 1 gather
__global__ __launch_bounds__(256) void spmm1_g(
    const int* __restrict__ ebase, const float* __restrict__ s_w,
    const int* __restrict__ s_en, const int* __restrict__ s_gn,
    const float* __restrict__ eg1, const float* __restrict__ rg1,
    const float* __restrict__ b_g1, float* __restrict__ out)
{
  const int gid = blockIdx.x * blockDim.x + threadIdx.x;
  const int d = gid >> 6, lane = gid & 63;
  if (d >= NNODE) return;
  const int p0 = ebase[d], p1 = ebase[d + 1];
  float4 acc = make_float4(0.f, 0.f, 0.f, 0.f);
  for (int p = p0; p < p1; ++p) {
    const float w = s_w[p];
    const int en = s_en[p], gn = s_gn[p];
    const float4 v = ((const float4*)(eg1 + (size_t)en * 256))[lane];
    const float4 u = ((const float4*)(rg1 + (size_t)gn * 256))[lane];
    acc.x += w * (v.x + u.x); acc.y += w * (v.y + u.y);
    acc.z += w * (v.z + u.z); acc.w += w * (v.w + u.w);
  }
  const float4 b = ((const float4*)b_g1)[lane];
  acc.x = fmaxf(acc.x + b.x, 0.f); acc.y = fmaxf(acc.y + b.y, 0.f);
  acc.z = fmaxf(acc.z + b.z, 0.f); acc.w = fmaxf(acc.w + b.w, 0.f);
  ((float4*)(out + (size_t)d * 256))[lane] = acc;
}

// ---------------- GCN layer 2 gather + fused score
__global__ __launch_bounds__(256) void spmm2_g(
    const int* __restrict__ ebase, const float* __restrict__ s_w,
    const int* __restrict__ s_src, const float* __restrict__ hg2,
    const float* __restrict__ b_g2, const float* __restrict__ W_e,
    float* __restrict__ h2, float* __restrict__ score)
{
  const int gid = blockIdx.x * blockDim.x + threadIdx.x;
  const int d = gid >> 6, lane = gid & 63;
  if (d >= NNODE) return;
  const int p0 = ebase[d], p1 = ebase[d + 1];
  float4 acc = make_float4(0.f, 0.f, 0.f, 0.f);
  if (lane < 50) {
    for (int p = p0; p < p1; ++p) {
      const float w = s_w[p];
      const int s = s_src[p];
      const float4 v = ((const float4*)(hg2 + (size_t)s * 200))[lane];
      acc.x += w * v.x; acc.y += w * v.y; acc.z += w * v.z; acc.w += w * v.w;
    }
    const float4 b = ((const float4*)b_g2)[lane];
    acc.x += b.x; acc.y += b.y; acc.z += b.z; acc.w += b.w;
    ((float4*)(h2 + (size_t)d * 200))[lane] = acc;
  }
  float s = 0.f;
  if (lane < 50) {
    const float4 we = ((const float4*)W_e)[lane];
    s = acc.x * we.x + acc.y * we.y + acc.z * we.z + acc.w * we.w;
  }
  for (int off = 32; off; off >>= 1) s += __shfl_down(s, off);
  if (lane == 0) score[d] = s;
}

// ---------------- per-entity softmax + weighted sum + mean
__global__ __launch_bounds__(256) void ent_k(
    const int* __restrict__ nbase, const int* __restrict__ node_of,
    const float* __restrict__ h2, const float* __restrict__ score,
    float* __restrict__ embE)
{
  const int gid = blockIdx.x * blockDim.x + threadIdx.x;
  const int ent = gid >> 6, lane = gid & 63;
  if (ent >= N_ENT) return;
  const int p0 = nbase[ent], p1 = nbase[ent + 1];
  const int cnt = p1 - p0;
  float m = -3.4e38f;
  for (int p = p0 + lane; p < p1; p += 64) m = fmaxf(m, score[node_of[p]]);
  #pragma unroll
  for (int off = 32; off; off >>= 1) m = fmaxf(m, __shfl_xor(m, off));
  float es = 0.f;
  for (int p = p0 + lane; p < p1; p += 64) es += __expf(score[node_of[p]] - m);
  #pragma unroll
  for (int off = 32; off; off >>= 1) es += __shfl_xor(es, off);
  const float inv_es = (cnt > 0) ? 1.f / es : 0.f;
  const float inv_cnt = 1.f / fmaxf((float)cnt, 1.f);
  float4 aw = make_float4(0.f, 0.f, 0.f, 0.f);
  float4 am = make_float4(0.f, 0.f, 0.f, 0.f);
  for (int p = p0; p < p1; ++p) {
    const int nd = node_of[p];
    const float z = __expf(score[nd] - m) * inv_es;
    if (lane < 50) {
      const float4 v = ((const float4*)(h2 + (size_t)nd * 200))[lane];
      aw.x += z * v.x; aw.y += z * v.y; aw.z += z * v.z; aw.w += z * v.w;
      am.x += v.x; am.y += v.y; am.z += v.z; am.w += v.w;
    }
  }
  if (lane < 50) {
    ((float4*)(embE + (size_t)ent * 400))[lane] = aw;
    float4 mn = make_float4(am.x * inv_cnt, am.y * inv_cnt, am.z * inv_cnt, am.w * inv_cnt);
    ((float4*)(embE + (size_t)ent * 400 + 200))[lane] = mn;
  }
}

extern "C" void kernel_launch(void* const* d_in, const int* in_sizes, int n_in,
                              void* d_out, int out_size, void* d_ws, size_t ws_size,
                              hipStream_t stream)
{
  const float* img  = (const float*)d_in[0];
  const float* txt  = (const float*)d_in[1];
  const float* rel  = (const float*)d_in[2];
  const float* W_it = (const float*)d_in[3];
  const float* b_it = (const float*)d_in[4];
  const float* W_ri = (const float*)d_in[5];
  const float* b_ri = (const float*)d_in[6];
  const float* W_g1 = (const float*)d_in[7];
  const float* b_g1 = (const float*)d_in[8];
  const float* W_g2 = (const float*)d_in[9];
  const float* b_g2 = (const float*)d_in[10];
  const float* W_e  = (const float*)d_in[11];
  const float* W_eo = (const float*)d_in[13];
  const float* b_eo = (const float*)d_in[14];
  const float* W_r  = (const float*)d_in[15];
  const float* b_r  = (const float*)d_in[16];
  const float* ew   = (const float*)d_in[17];
  const int*   bx   = (const int*)d_in[18];
  const int*   bg   = (const int*)d_in[19];
  const int*   esrc = (const int*)d_in[20];
  const int*   edst = (const int*)d_in[21];

  float* ws = (float*)d_ws;
  size_t off = 0;
  auto alloc = [&](size_t n){ size_t r = off; off += (n + 255) & ~(size_t)255; return r; };
  float* emf  = ws + alloc((size_t)N_ENT * 100);
  float* rin  = ws + alloc((size_t)N_REL * 100);
  float* eg1  = ws + alloc((size_t)N_ENT * 256);
  float* rg1  = ws + alloc((size_t)N_REL * 256);
  float* big1 = ws + alloc((size_t)NNODE * 256);   // h1; first NNODE*200 reused as h2
  float* hg2  = ws + alloc((size_t)NNODE * 200);   // also aliases enc split-K partials
  float* embE = ws + alloc((size_t)N_ENT * 400);
  float* score = ws + alloc(NNODE);
  int* ehist = (int*)(ws + alloc(NNODE));
  int* ecur  = (int*)(ws + alloc(NNODE));
  int* ebase = (int*)(ws + alloc(NNODE + 1));
  int* nhist = (int*)(ws + alloc(N_ENT));
  int* ncur  = (int*)(ws + alloc(N_ENT));
  int* nbase = (int*)(ws + alloc(N_ENT + 1));
  int* epart = (int*)(ws + alloc(256));
  int* npart = (int*)(ws + alloc(256));
  float* s_w  = ws + alloc(NEDGE);
  int* s_src  = (int*)(ws + alloc(NEDGE));
  int* s_en   = (int*)(ws + alloc(NEDGE));
  int* s_gn   = (int*)(ws + alloc(NEDGE));
  int* node_of = (int*)(ws + alloc(NNODE));
  unsigned short* Wt1 = (unsigned short*)(ws + alloc((size_t)NP_ENC * KP_ENC / 2));
  unsigned short* Wt2 = (unsigned short*)(ws + alloc((size_t)208 * 256 / 2));
  float* part = hg2;
  float* h2 = big1;

  dim3 blk(256);

  // ---- CSR builds (hist -> 3-phase scan -> scatter)
  hipMemsetAsync(ehist, 0, (size_t)NNODE * 4, stream);
  hipMemsetAsync(ecur,  0, (size_t)NNODE * 4, stream);
  hipMemsetAsync(nhist, 0, (size_t)N_ENT * 4, stream);
  hipMemsetAsync(ncur,  0, (size_t)N_ENT * 4, stream);
  hist_k<<<ceil_div(NEDGE, 256), blk, 0, stream>>>(edst, ehist, NEDGE);
  hist_k<<<ceil_div(NNODE, 256), blk, 0, stream>>>(bx, nhist, NNODE);
  scan1_k<<<ceil_div(NNODE, 1024), blk, 0, stream>>>(ehist, ebase, epart, NNODE);
  scan2_k<<<1, blk, 0, stream>>>(epart, ceil_div(NNODE, 1024), ebase + NNODE);
  scan3_k<<<ceil_div(NNODE, 256), blk, 0, stream>>>(ebase, epart, NNODE);
  scan1_k<<<ceil_div(N_ENT, 1024), blk, 0, stream>>>(nhist, nbase, npart, N_ENT);
  scan2_k<<<1, blk, 0, stream>>>(npart, ceil_div(N_ENT, 1024), nbase + N_ENT);
  scan3_k<<<ceil_div(N_ENT, 256), blk, 0, stream>>>(nbase, npart, N_ENT);
  edge_scatter_k<<<ceil_div(NEDGE, 256), blk, 0, stream>>>(
      esrc, edst, ew, bx, bg, ebase, ecur, s_w, s_src, s_en, s_gn);
  node_scatter_k<<<ceil_div(NNODE, 256), blk, 0, stream>>>(bx, nbase, ncur, node_of);

  // ---- weight prep (bf16 transposed)
  wt1_k<<<dim3(ceil_div(KP_ENC, 256), NP_ENC), blk, 0, stream>>>(W_it, Wt1);
  wt2_k<<<ceil_div(208 * 256, 256), blk, 0, stream>>>(W_g2, Wt2);

  // ---- encoder: MFMA split-K + reduce
  enc_mfma<<<dim3(MP_ENC / 64, 4), blk, 0, stream>>>(img, txt, Wt1, part);
  enc_reduce<<<ceil_div(N_ENT * 100, 256), blk, 0, stream>>>(part, b_it, emf);

  // ---- small f32 GEMMs
  gemm_f32<true, true><<<dim3(1, ceil_div(N_REL, 64)), blk, 0, stream>>>(
      rel, 300, rel, W_ri, b_ri, rin, N_REL, 300, 100);
  gemm_f32<false, false><<<dim3(2, ceil_div(N_ENT, 64)), blk, 0, stream>>>(
      emf, 100, emf, W_g1, nullptr, eg1, N_ENT, 100, 256);
  gemm_f32<false, false><<<dim3(2, ceil_div(N_REL, 64)), blk, 0, stream>>>(
      rin, 100, rin, W_g1 + 100 * 256, nullptr, rg1, N_REL, 100, 256);

  // ---- GCN layer 1 (gather, fused bias+relu)
  spmm1_g<<<ceil_div(NNODE * 64, 256), blk, 0, stream>>>(
      ebase, s_w, s_en, s_gn, eg1, rg1, b_g1, big1);

  // ---- GCN layer 2: MFMA GEMM then gather + fused score
  gemm2_mfma<<<NNODE / 64, blk, 0, stream>>>(big1, Wt2, hg2);
  spmm2_g<<<ceil_div(NNODE * 64, 256), blk, 0, stream>>>(
      ebase, s_w, s_src, hg2, b_g2, W_e, h2, score);

  // ---- per-entity softmax + weighted sum + mean
  ent_k<<<ceil_div(N_ENT * 64, 256), blk, 0, stream>>>(nbase, node_of, h2, score, embE);

  // ---- final projections
  float* out_new = (float*)d_out;
  float* out_rel = out_new + (size_t)N_ENT * 200;
  gemm_f32<false, true><<<dim3(2, ceil_div(N_ENT, 64)), blk, 0, stream>>>(
      embE, 400, embE, W_eo, b_eo, out_new, N_ENT, 400, 200);
  gemm_f32<true, true><<<dim3(2, ceil_div(N_REL, 64)), blk, 0, stream>>>(
      rel, 300, rel, W_r, b_r, out_rel, N_REL, 300, 200);
}